// Round 24
// baseline (43836.224 us; speedup 1.0000x reference)
//
#include <hip/hip_runtime.h>
#include <math.h>

// DenseLSTMForecast: B=256, T=1024, H=128, FUTURE=32.
// R17 (2nd submit; round 23 "container failed twice" = infra signature
// previously seen on a kernel that later passed; audit found no defect).
// R17: R16 + per-wave RELEASE flags -> barrier diet (core 3->2, helper 4->3).
// R16 post-mortem (5760us best): WRITE_SIZE 3.67->2.04GB exactly as
// predicted (half-split fixed the RMW double-write). Step ~13.1k cy =
// LDS ~7.2k (768 wave-instr, G=4 decomposition is at its traffic optimum)
// + VALU 4.7k (hidden) + ~6k barriers.
// Residual attack: B3(core)/B4(helper) exist only to drain ring stores
// before tid0's flag add. Replace with per-wave lane0 RELEASE fetch_add:
// release atomics drain the WAVE's outstanding stores first; consumer
// observing count==16*(t+1) has synced-with all 16 wave releases (release
// sequence through RMWs) => all stores visible. Flag targets scale x16.
// LDS hazards formerly fenced by the deleted barrier are re-covered by
// next iter's B1 (audited: gs/ps, hown, hin/xs).
// Everything else byte-identical to measured R16: G=4 gate-contiguous dot
// (512 b128 reads), permuted LDS partials, half-split RP rings, fused
// combine+activation, 1024-thr blocks, consumer-gated helper anti-deps.
// Geometry: 32 groups x 8 rows, 224 WGs, 7 stages:
//   s0 c1-core   : g1 = xw1*x+b1 + Whh1*h1           -> RH1 ring
//   s1 c2-helper : p2 = xw2*x+b2 + Wih2[:,1:]*h1(t)  -> RP2 ring (half-split)
//   s2 c2-core   : g2 = p2 + Whh2*h2                 -> RH2 ring
//   s3 c3-helperA: pA = xw3*x+b3 + Wih3[:,1:129]*h1  -> RP3A ring (half-split)
//   s4 c3-helperB: pB = Wih3[:,129:257]*h2           -> RP3B ring (half-split)
//   s5 c3-core   : g3 = pA+pB + Whh3*h3              -> RH3 ring
//   s6 head      : o = Wlin.[x,h1,h2,h3]+b           -> RO ring + out
// Prediction: dur 5760 -> 5000-5400us, VALU 39-43%. Flat: barriers cheap,
// residual irreducible here. REGRESSION toward 6ms: 16 serialized flag
// RMWs cost more than the barrier -> revert core release, keep helper's.

#define TSEQ 1024
#define HH   128
#define TT   1056
#define THR  1024
#define NW   16                    // waves per block; flag quantum

// ---- ws dword offsets (identical to R7) ----
#define PLANES   0                 // 6 planes x [128 k][512 g] fp32
#define SCAL     393216            // xw1,xw2,xw3,bs1,bs2,bs3 (512 each)
#define WLIN     396288            // Wlin[0..384], [385]=b_lin, pad 512
#define XT       396800            // x transposed [1024][256]
#define RH1      658944            // h rings: [16][256][128] fp32
#define RH2      1183232
#define RH3      1707520
#define RO       2231808           // o ring [16][256] fp32
#define RP2      2235904           // partial rings: [8][256][512] fp32 (half-split perm)
#define RP3A     3284480
#define RP3B     4333056
#define FLAGS    5381632           // 224 x 32-dword lines
#define PREP_TOT 666112            // 658944 + 7168 (flags zeroing)

#define RH1_64 (RH1/2)
#define RH2_64 (RH2/2)
#define RH3_64 (RH3/2)

typedef unsigned long long u64;

__device__ __forceinline__ float sigmoidf_(float v) {
  return 1.0f / (1.0f + expf(-v));
}

__device__ __forceinline__ void wait_c(unsigned* p, unsigned tgt, unsigned& cached) {
  if (cached >= tgt) return;
  unsigned v = __hip_atomic_load(p, __ATOMIC_ACQUIRE, __HIP_MEMORY_SCOPE_AGENT);
  while (v < tgt) {
    __builtin_amdgcn_s_sleep(1);
    v = __hip_atomic_load(p, __ATOMIC_ACQUIRE, __HIP_MEMORY_SCOPE_AGENT);
  }
  cached = v;
}

// per-wave release: lane0 of each wave; drains the wave's stores first.
__device__ __forceinline__ void wave_release(unsigned* f, int tid) {
  if ((tid & 63) == 0)
    __hip_atomic_fetch_add(f, 1u, __ATOMIC_RELEASE, __HIP_MEMORY_SCOPE_AGENT);
}

// ---------------------------------------------------------------------------
__global__ void prep_kernel(const float* __restrict__ x,
                            const float* __restrict__ Wih1, const float* __restrict__ Whh1,
                            const float* __restrict__ bih1, const float* __restrict__ bhh1,
                            const float* __restrict__ Wih2, const float* __restrict__ Whh2,
                            const float* __restrict__ bih2, const float* __restrict__ bhh2,
                            const float* __restrict__ Wih3, const float* __restrict__ Whh3,
                            const float* __restrict__ bih3, const float* __restrict__ bhh3,
                            const float* __restrict__ Wlin, const float* __restrict__ blin,
                            float* __restrict__ ws) {
  int idx = blockIdx.x * 256 + threadIdx.x;
  if (idx < SCAL) {
    int p = idx >> 16;            // plane
    int rem = idx & 65535;
    int k = rem >> 9, g = rem & 511;
    float v;
    switch (p) {
      case 0:  v = Whh1[g * HH + k];         break;
      case 1:  v = Wih2[g * 129 + 1 + k];    break;
      case 2:  v = Whh2[g * HH + k];         break;
      case 3:  v = Wih3[g * 257 + 1 + k];    break;
      case 4:  v = Wih3[g * 257 + 129 + k];  break;
      default: v = Whh3[g * HH + k];         break;
    }
    ws[idx] = v;
  } else if (idx < WLIN) {
    int r = idx - SCAL;
    float v;
    if      (r < 512)  v = Wih1[r];
    else if (r < 1024) v = Wih2[(r - 512) * 129];
    else if (r < 1536) v = Wih3[(r - 1024) * 257];
    else if (r < 2048) v = bih1[r - 1536] + bhh1[r - 1536];
    else if (r < 2560) v = bih2[r - 2048] + bhh2[r - 2048];
    else               v = bih3[r - 2560] + bhh3[r - 2560];
    ws[idx] = v;
  } else if (idx < XT) {
    int j = idx - WLIN;
    ws[idx] = (j < 385) ? Wlin[j] : (j == 385 ? blin[0] : 0.0f);
  } else if (idx < RH1) {
    int j = idx - XT;
    int t = j >> 8, r = j & 255;
    ws[idx] = x[r * TSEQ + t];
  } else if (idx < PREP_TOT) {
    ws[FLAGS + (idx - RH1)] = 0.0f;   // zero flag lines (ws is poisoned)
  }
}

// ---------------------------------------------------------------------------
// G=4 K/8 dot for one row: 16 k-values, 4 gates of unit ud.
// hb pre-offset to the row base + kq*16. Returns acc as float4 (gate order).
__device__ __forceinline__ float4 dot16_g4(const float w[4][16],
                                           const float* __restrict__ hb) {
  float a0 = 0.f, a1 = 0.f, a2 = 0.f, a3 = 0.f;
  #pragma unroll
  for (int k4 = 0; k4 < 4; ++k4) {
    const float4 h4 = *(const float4*)&hb[k4 * 4];
    #pragma unroll
    for (int j = 0; j < 4; ++j) {
      const float hv = (j == 0) ? h4.x : (j == 1) ? h4.y : (j == 2) ? h4.z : h4.w;
      a0 = fmaf(w[0][4 * k4 + j], hv, a0);
      a1 = fmaf(w[1][4 * k4 + j], hv, a1);
      a2 = fmaf(w[2][4 * k4 + j], hv, a2);
      a3 = fmaf(w[3][4 * k4 + j], hv, a3);
    }
  }
  return make_float4(a0, a1, a2, a3);
}

// ---------------------------------------------------------------------------
// Core stage: gates = Whh*h_own (G=4 x K/8, permuted partials) + add-terms.
// 2 barriers/step: B1 (grant + gs/hown hazard fence), B2 (partials visible).
// Ring stores drained by per-wave release.
template <int SSELF, int SWA, int SWB, int NP, int XF, int PB, int PR1, int PR2, int DRH>
__device__ void core_stage(float* __restrict__ wsm, char* SB, int g) {
  const int tid = threadIdx.x;              // [0,1024)
  const int r0 = g * 8;
  float* gs   = (float*)SB;                 // [8 rows][8 kq][512 colp] = 131072 B
  float* hown = (float*)(SB + 131072);      // [8][128] = 4096 B

  u64* ws64 = (u64*)wsm;
  unsigned* flagb = (unsigned*)wsm + FLAGS;
  unsigned* Fself = flagb + (size_t)(SSELF * 32 + g) * 32;
  unsigned* Fh    = flagb + (size_t)(6 * 32 + g) * 32;
  unsigned ca = 0, cb = 0, ch = 0;

  // dot role: unit ud owns gate cols {ud+128q}, k-range [kq*16, kq*16+16)
  const int ud = tid & 127, kq = tid >> 7;
  float w[4][16];
  #pragma unroll
  for (int q = 0; q < 4; ++q)
    #pragma unroll
    for (int k = 0; k < 16; ++k)
      w[q][k] = wsm[(size_t)PB * 65536 + (size_t)(kq * 16 + k) * 512 + ud + 128 * q];

  // combine+activation role: (row, u)
  const int row = tid >> 7, u = tid & 127;
  float xw4[4], bs4[4];
  if (XF) {
    #pragma unroll
    for (int q = 0; q < 4; ++q) {
      xw4[q] = wsm[SCAL + q * 128 + u];
      bs4[q] = wsm[SCAL + 1536 + q * 128 + u];
    }
  }

  hown[tid & 1023] = 0.f;                   // 8*128 = 1024 = blockDim
  float cst = 0.f;
  __syncthreads();

  for (int t = 0; t < TT; ++t) {
    if (tid == 0) {
      if constexpr (SWA >= 0)
        wait_c(flagb + (size_t)(SWA * 32 + g) * 32, (unsigned)(NW * (t + 1)), ca);
      if constexpr (SWB >= 0)
        wait_c(flagb + (size_t)(SWB * 32 + g) * 32, (unsigned)(NW * (t + 1)), cb);
      unsigned ht = (t >= 15) ? (unsigned)(t - 14) : 0u;
      if (XF && t >= TSEQ && (unsigned)t > ht) ht = (unsigned)t;
      if (ht) wait_c(Fh, (unsigned)(NW * ht), ch);
    }
    __syncthreads();                 // B1: grant + gs/hown hazard fence
    const int slot = t & 15;

    // combine-role prefetch: ring add-terms (HALF-SPLIT permutation):
    // gates{0,1} packed at u64 col u; gates{2,3} at u64 col 128+u.
    float pa[4], pb[4], xr;
    if constexpr (NP >= 1) {
      u64 l0 = __hip_atomic_load(
          ws64 + (size_t)(PR1 / 2) + (size_t)(t & 7) * 65536 +
              (size_t)(r0 + row) * 256 + u,
          __ATOMIC_RELAXED, __HIP_MEMORY_SCOPE_AGENT);
      u64 l1 = __hip_atomic_load(
          ws64 + (size_t)(PR1 / 2) + (size_t)(t & 7) * 65536 +
              (size_t)(r0 + row) * 256 + 128 + u,
          __ATOMIC_RELAXED, __HIP_MEMORY_SCOPE_AGENT);
      pa[0] = __builtin_bit_cast(float, (unsigned)(l0 & 0xffffffffu));
      pa[1] = __builtin_bit_cast(float, (unsigned)(l0 >> 32));
      pa[2] = __builtin_bit_cast(float, (unsigned)(l1 & 0xffffffffu));
      pa[3] = __builtin_bit_cast(float, (unsigned)(l1 >> 32));
    }
    if constexpr (NP == 2) {
      u64 l0 = __hip_atomic_load(
          ws64 + (size_t)(PR2 / 2) + (size_t)(t & 7) * 65536 +
              (size_t)(r0 + row) * 256 + u,
          __ATOMIC_RELAXED, __HIP_MEMORY_SCOPE_AGENT);
      u64 l1 = __hip_atomic_load(
          ws64 + (size_t)(PR2 / 2) + (size_t)(t & 7) * 65536 +
              (size_t)(r0 + row) * 256 + 128 + u,
          __ATOMIC_RELAXED, __HIP_MEMORY_SCOPE_AGENT);
      pb[0] = __builtin_bit_cast(float, (unsigned)(l0 & 0xffffffffu));
      pb[1] = __builtin_bit_cast(float, (unsigned)(l0 >> 32));
      pb[2] = __builtin_bit_cast(float, (unsigned)(l1 & 0xffffffffu));
      pb[3] = __builtin_bit_cast(float, (unsigned)(l1 >> 32));
    }
    if (XF) {
      if (t < TSEQ) {
        xr = wsm[XT + (size_t)t * 256 + r0 + row];
      } else {
        unsigned uu = __hip_atomic_load(
            (unsigned*)wsm + RO + (size_t)((t - 1) & 15) * 256 + r0 + row,
            __ATOMIC_RELAXED, __HIP_MEMORY_SCOPE_AGENT);
        xr = __builtin_bit_cast(float, uu);
      }
    }

    // dot: per row accumulate-then-store (acc live range = 4)
    #pragma unroll
    for (int a = 0; a < 8; ++a) {
      const float4 acc = dot16_g4(w, hown + a * HH + kq * 16);
      *(float4*)&gs[a * 4096 + kq * 512 + 4 * ud] = acc;
    }
    __syncthreads();                 // B2: partials visible

    // fused combine + activation: sum 8 contiguous-b128 partials
    {
      float gv0, gv1, gv2, gv3;
      if constexpr (NP == 0) {
        gv0 = fmaf(xw4[0], xr, bs4[0]);
        gv1 = fmaf(xw4[1], xr, bs4[1]);
        gv2 = fmaf(xw4[2], xr, bs4[2]);
        gv3 = fmaf(xw4[3], xr, bs4[3]);
      } else if constexpr (NP == 1) {
        gv0 = pa[0]; gv1 = pa[1]; gv2 = pa[2]; gv3 = pa[3];
      } else {
        gv0 = pa[0] + pb[0]; gv1 = pa[1] + pb[1];
        gv2 = pa[2] + pb[2]; gv3 = pa[3] + pb[3];
      }
      #pragma unroll
      for (int p = 0; p < 8; ++p) {
        const float4 f = *(const float4*)&gs[row * 4096 + p * 512 + 4 * u];
        gv0 += f.x; gv1 += f.y; gv2 += f.z; gv3 += f.w;
      }
      const float c = sigmoidf_(gv1) * cst + sigmoidf_(gv0) * tanhf(gv2);
      cst = c;
      const float h = sigmoidf_(gv3) * tanhf(c);
      hown[row * HH + u] = h;
      __hip_atomic_store(
          (unsigned*)wsm + DRH + (size_t)slot * 32768 + (size_t)(r0 + row) * 128 + u,
          __builtin_bit_cast(unsigned, h),
          __ATOMIC_RELAXED, __HIP_MEMORY_SCOPE_AGENT);
    }
    // per-wave release: drains this wave's h-ring stores, no block barrier
    wave_release(Fself, tid);
  }
}

// ---------------------------------------------------------------------------
// Helper stage: partial = [x-term+bias if XF] + Wpart * h_src(t) (G=4 x K/8,
// permuted partials); combine; publish HALF-SPLIT to partial ring.
// 3 barriers/step: B1 (grant + ps/hin/xs fence), B2 (hin), B3 (partials).
// Ring stores drained by per-wave release.
template <int SSELF, int SW, int SC, int XF, int PB, int SI, int SRH64, int DRP>
__device__ void helper_stage(float* __restrict__ wsm, char* SB, int g) {
  const int tid = threadIdx.x;
  const int r0 = g * 8;
  float* ps  = (float*)SB;                  // [8][8][512] = 131072 B
  float* hin = (float*)(SB + 131072);       // [8][128] = 4096 B
  float* xs  = (float*)(SB + 135168);       // [8]

  u64* ws64 = (u64*)wsm;
  unsigned* flagb = (unsigned*)wsm + FLAGS;
  unsigned* Fself = flagb + (size_t)(SSELF * 32 + g) * 32;
  unsigned* Fw    = flagb + (size_t)(SW * 32 + g) * 32;
  unsigned* Fc    = flagb + (size_t)(SC * 32 + g) * 32;
  unsigned* Fhd   = flagb + (size_t)(6 * 32 + g) * 32;
  unsigned cw = 0, cc = 0, chd = 0;

  const int ud = tid & 127, kq = tid >> 7;
  float w[4][16];
  #pragma unroll
  for (int q = 0; q < 4; ++q)
    #pragma unroll
    for (int k = 0; k < 16; ++k)
      w[q][k] = wsm[(size_t)PB * 65536 + (size_t)(kq * 16 + k) * 512 + ud + 128 * q];

  const int row = tid >> 7, u = tid & 127;
  float xw4[4], bs4[4];
  if (XF) {
    #pragma unroll
    for (int q = 0; q < 4; ++q) {
      xw4[q] = wsm[SCAL + SI * 512 + q * 128 + u];
      bs4[q] = wsm[SCAL + 1536 + SI * 512 + q * 128 + u];
    }
  }
  __syncthreads();

  for (int t = 0; t < TT; ++t) {
    if (tid == 0) {
      wait_c(Fw, (unsigned)(NW * (t + 1)), cw);
      if (t >= 7) wait_c(Fc, (unsigned)(NW * (t - 6)), cc);
      if (XF && t >= TSEQ) wait_c(Fhd, (unsigned)(NW * t), chd);
    }
    __syncthreads();                 // B1: grant + ps/hin/xs hazard fence
    const int slot = t & 15;

    if (XF) {
      if (tid < 8) {
        float xv;
        if (t < TSEQ) {
          xv = wsm[XT + (size_t)t * 256 + r0 + tid];
        } else {
          unsigned uu = __hip_atomic_load(
              (unsigned*)wsm + RO + (size_t)((t - 1) & 15) * 256 + r0 + tid,
              __ATOMIC_RELAXED, __HIP_MEMORY_SCOPE_AGENT);
          xv = __builtin_bit_cast(float, uu);
        }
        xs[tid] = xv;
      }
    }
    // stage h_src(t): 512 u64 / first 512 threads
    if (tid < 512) {
      const int a = tid >> 6, up = tid & 63;
      u64 v = __hip_atomic_load(
          ws64 + SRH64 + (size_t)slot * 16384 + (size_t)(r0 + a) * 64 + up,
          __ATOMIC_RELAXED, __HIP_MEMORY_SCOPE_AGENT);
      *(u64*)&hin[a * HH + up * 2] = v;
    }
    __syncthreads();                 // B2: hin (and xs) visible

    // dot: per row accumulate-then-store
    #pragma unroll
    for (int a = 0; a < 8; ++a) {
      const float4 acc = dot16_g4(w, hin + a * HH + kq * 16);
      *(float4*)&ps[a * 4096 + kq * 512 + 4 * ud] = acc;
    }
    __syncthreads();                 // B3: partials visible

    // combine + publish (HALF-SPLIT ring: lane-consecutive u64 stores)
    {
      float v0, v1, v2, v3;
      if (XF) {
        const float xv = xs[row];
        v0 = fmaf(xw4[0], xv, bs4[0]);
        v1 = fmaf(xw4[1], xv, bs4[1]);
        v2 = fmaf(xw4[2], xv, bs4[2]);
        v3 = fmaf(xw4[3], xv, bs4[3]);
      } else {
        v0 = v1 = v2 = v3 = 0.f;
      }
      #pragma unroll
      for (int p = 0; p < 8; ++p) {
        const float4 f = *(const float4*)&ps[row * 4096 + p * 512 + 4 * u];
        v0 += f.x; v1 += f.y; v2 += f.z; v3 += f.w;
      }
      const u64 s0 = ((u64)__builtin_bit_cast(unsigned, v1) << 32) |
                     (u64)__builtin_bit_cast(unsigned, v0);
      const u64 s1 = ((u64)__builtin_bit_cast(unsigned, v3) << 32) |
                     (u64)__builtin_bit_cast(unsigned, v2);
      __hip_atomic_store(
          ws64 + (size_t)(DRP / 2) + (size_t)(t & 7) * 65536 +
              (size_t)(r0 + row) * 256 + u, s0,
          __ATOMIC_RELAXED, __HIP_MEMORY_SCOPE_AGENT);
      __hip_atomic_store(
          ws64 + (size_t)(DRP / 2) + (size_t)(t & 7) * 65536 +
              (size_t)(r0 + row) * 256 + 128 + u, s1,
          __ATOMIC_RELAXED, __HIP_MEMORY_SCOPE_AGENT);
    }
    // per-wave release: drains this wave's ring stores, no block barrier
    wave_release(Fself, tid);
  }
}

// ---------------------------------------------------------------------------
__device__ void head_stage(float* __restrict__ wsm, char* SB, int g,
                           float* __restrict__ out) {
  const int tid = threadIdx.x;
  const int r0 = g * 8;
  float* hin  = (float*)SB;                 // [3][8][128] = 12288 B
  float* obuf = (float*)(SB + 12288);       // [8][32]

  u64* ws64 = (u64*)wsm;
  unsigned* flagb = (unsigned*)wsm + FLAGS;
  unsigned* Fself = flagb + (size_t)(6 * 32 + g) * 32;
  unsigned* Fc3   = flagb + (size_t)(5 * 32 + g) * 32;
  unsigned c3c = 0;

  const int row = (tid >> 6) & 7, lane = tid & 63;
  float wlr[6];
  #pragma unroll
  for (int q = 0; q < 6; ++q) wlr[q] = wsm[WLIN + 1 + lane + 64 * q];
  const float wl0 = wsm[WLIN];
  const float blv = wsm[WLIN + 385];
  float xv = wsm[XT + r0 + row];

  for (int t = 0; t < TT; ++t) {
    if (tid == 0) wait_c(Fc3, (unsigned)(NW * (t + 1)), c3c);
    __syncthreads();                 // B1
    const int slot = t & 15;

    #pragma unroll
    for (int i = 0; i < 2; ++i) {
      const int idx = tid + i * 1024;       // 0..2047, use 0..1535
      if (idx < 1536) {
        const int s = idx >> 9, rem = idx & 511;
        const int a = rem >> 6, up = rem & 63;
        const size_t base = (s == 0) ? (size_t)RH1_64 : (s == 1) ? (size_t)RH2_64 : (size_t)RH3_64;
        u64 v = __hip_atomic_load(
            ws64 + base + (size_t)slot * 16384 + (size_t)(r0 + a) * 64 + up,
            __ATOMIC_RELAXED, __HIP_MEMORY_SCOPE_AGENT);
        *(u64*)&hin[(s * 8 + a) * HH + up * 2] = v;
      }
    }
    __syncthreads();                 // B2

    if (tid < 512) {
      float s = 0.f;
      #pragma unroll
      for (int q = 0; q < 6; ++q) {
        const int j = lane + 64 * q;        // 0..383
        const int si = j >> 7, uu = j & 127;
        s = fmaf(wlr[q], hin[(si * 8 + row) * HH + uu], s);
      }
      #pragma unroll
      for (int off = 32; off > 0; off >>= 1) s += __shfl_down(s, off, 64);
      if (lane == 0) {
        const float o = s + fmaf(wl0, xv, blv);
        obuf[row * 32 + (t & 31)] = o;
        __hip_atomic_store((unsigned*)wsm + RO + (size_t)slot * 256 + r0 + row,
                           __builtin_bit_cast(unsigned, o),
                           __ATOMIC_RELAXED, __HIP_MEMORY_SCOPE_AGENT);
        xv = (t + 1 < TSEQ) ? wsm[XT + (size_t)(t + 1) * 256 + r0 + row] : o;
      }
    }
    __syncthreads();                 // B3: o-store + obuf drained
    wave_release(Fself, tid);        // 16 increments/step (consistent scale)

    if ((t & 31) == 31) {
      const int tb = t - 31;
      if (tid < 256) {
        const int a = tid >> 5, m = tid & 31;
        out[(size_t)(r0 + a) * TT + tb + m] = obuf[a * 32 + m];
      }
    }
  }
}

// ---------------------------------------------------------------------------
__global__ __launch_bounds__(1024)
void lstm_kernel(float* __restrict__ wsm, float* __restrict__ out) {
  __shared__ __align__(16) char SB[135232];
  const int s = blockIdx.x >> 5, g = blockIdx.x & 31;
  switch (s) {
    case 0: core_stage<0, -1, -1, 0, 1, 0, 0, 0, RH1>(wsm, SB, g); break;
    case 1: helper_stage<1, 0, 2, 1, 1, 1, RH1_64, RP2>(wsm, SB, g); break;
    case 2: core_stage<2, 1, -1, 1, 0, 2, RP2, 0, RH2>(wsm, SB, g); break;
    case 3: helper_stage<3, 0, 5, 1, 3, 2, RH1_64, RP3A>(wsm, SB, g); break;
    case 4: helper_stage<4, 2, 5, 0, 4, 0, RH2_64, RP3B>(wsm, SB, g); break;
    case 5: core_stage<5, 3, 4, 2, 0, 5, RP3A, RP3B, RH3>(wsm, SB, g); break;
    default: head_stage(wsm, SB, g, out); break;
  }
}

// ---------------------------------------------------------------------------
extern "C" void kernel_launch(void* const* d_in, const int* in_sizes, int n_in,
                              void* d_out, int out_size, void* d_ws, size_t ws_size,
                              hipStream_t stream) {
  const float* x    = (const float*)d_in[0];
  const float* Wih1 = (const float*)d_in[1];
  const float* Whh1 = (const float*)d_in[2];
  const float* bih1 = (const float*)d_in[3];
  const float* bhh1 = (const float*)d_in[4];
  const float* Wih2 = (const float*)d_in[5];
  const float* Whh2 = (const float*)d_in[6];
  const float* bih2 = (const float*)d_in[7];
  const float* bhh2 = (const float*)d_in[8];
  const float* Wih3 = (const float*)d_in[9];
  const float* Whh3 = (const float*)d_in[10];
  const float* bih3 = (const float*)d_in[11];
  const float* bhh3 = (const float*)d_in[12];
  const float* Wlin = (const float*)d_in[13];
  const float* blin = (const float*)d_in[14];
  float* ws  = (float*)d_ws;
  float* out = (float*)d_out;

  prep_kernel<<<PREP_TOT / 256, 256, 0, stream>>>(
      x, Wih1, Whh1, bih1, bhh1, Wih2, Whh2, bih2, bhh2,
      Wih3, Whh3, bih3, bhh3, Wlin, blin, ws);
  lstm_kernel<<<224, THR, 0, stream>>>(ws, out);
}

// Round 25
// 5732.492 us; speedup vs baseline: 7.6470x; 7.6470x over previous
//
#include <hip/hip_runtime.h>
#include <math.h>

// DenseLSTMForecast: B=256, T=1024, H=128, FUTURE=32.
// R18 = R16 VERBATIM REVERT (verified 5760us, session best).
// R17 post-mortem (43836us, VALU 4.8%): per-wave RELEASE flags are toxic —
// agent-scope release RMW is heavyweight (vmcnt drain + L2-level ordering),
// and 16/step/block contending on one flag line replaced a ~1.5k-cy barrier
// with ~25k cy of serialized release traffic. Combined with R12 (all-thread
// acquire polling, 30ms): cross-block sync on this fabric MUST be
// block-barrier -> single tid0 increment. Never distribute sync across waves.
// Session ladder (all measured): 8150 (R7) -> 6806 (R14, LDS reads 2048->1024)
// -> 6333 (R15, G=4 gate-contiguous, reads->512) -> 5760 (R16, half-split
// RP rings fixed RMW double-write). Barrier/grant residual (~6k cy/step)
// resisted 3 structurally different removal attempts -> practical floor
// for this 7-stage pipeline structure.
// Structure: G=4 gate-contiguous dot (512 b128 broadcast reads/CU/step),
// permuted LDS partials gs[row][kq][4u+q] (b128 stores + fused
// combine+activation), half-split RP rings (lane-consecutive u64 stores),
// 1024-thr blocks (16 waves, 4 waves/SIMD), tid0 poll + B1 grant,
// consumer-gated helper anti-deps, head-gated core h-rings.
// Geometry: 32 groups x 8 rows, 224 WGs, 7 stages:
//   s0 c1-core   : g1 = xw1*x+b1 + Whh1*h1           -> RH1 ring
//   s1 c2-helper : p2 = xw2*x+b2 + Wih2[:,1:]*h1(t)  -> RP2 ring (half-split)
//   s2 c2-core   : g2 = p2 + Whh2*h2                 -> RH2 ring
//   s3 c3-helperA: pA = xw3*x+b3 + Wih3[:,1:129]*h1  -> RP3A ring (half-split)
//   s4 c3-helperB: pB = Wih3[:,129:257]*h2           -> RP3B ring (half-split)
//   s5 c3-core   : g3 = pA+pB + Whh3*h3              -> RH3 ring
//   s6 head      : o = Wlin.[x,h1,h2,h3]+b           -> RO ring + out
// Prediction: reproduce round-22: dur ~5760+-150us, VALU ~35.5%, Occ ~42%,
// WRITE ~2.04GB.

#define TSEQ 1024
#define HH   128
#define TT   1056
#define THR  1024

// ---- ws dword offsets (identical to R7) ----
#define PLANES   0                 // 6 planes x [128 k][512 g] fp32
#define SCAL     393216            // xw1,xw2,xw3,bs1,bs2,bs3 (512 each)
#define WLIN     396288            // Wlin[0..384], [385]=b_lin, pad 512
#define XT       396800            // x transposed [1024][256]
#define RH1      658944            // h rings: [16][256][128] fp32
#define RH2      1183232
#define RH3      1707520
#define RO       2231808           // o ring [16][256] fp32
#define RP2      2235904           // partial rings: [8][256][512] fp32 (half-split perm)
#define RP3A     3284480
#define RP3B     4333056
#define FLAGS    5381632           // 224 x 32-dword lines
#define PREP_TOT 666112            // 658944 + 7168 (flags zeroing)

#define RH1_64 (RH1/2)
#define RH2_64 (RH2/2)
#define RH3_64 (RH3/2)

typedef unsigned long long u64;

__device__ __forceinline__ float sigmoidf_(float v) {
  return 1.0f / (1.0f + expf(-v));
}

__device__ __forceinline__ void wait_c(unsigned* p, unsigned tgt, unsigned& cached) {
  if (cached >= tgt) return;
  unsigned v = __hip_atomic_load(p, __ATOMIC_ACQUIRE, __HIP_MEMORY_SCOPE_AGENT);
  while (v < tgt) {
    __builtin_amdgcn_s_sleep(1);
    v = __hip_atomic_load(p, __ATOMIC_ACQUIRE, __HIP_MEMORY_SCOPE_AGENT);
  }
  cached = v;
}

// ---------------------------------------------------------------------------
__global__ void prep_kernel(const float* __restrict__ x,
                            const float* __restrict__ Wih1, const float* __restrict__ Whh1,
                            const float* __restrict__ bih1, const float* __restrict__ bhh1,
                            const float* __restrict__ Wih2, const float* __restrict__ Whh2,
                            const float* __restrict__ bih2, const float* __restrict__ bhh2,
                            const float* __restrict__ Wih3, const float* __restrict__ Whh3,
                            const float* __restrict__ bih3, const float* __restrict__ bhh3,
                            const float* __restrict__ Wlin, const float* __restrict__ blin,
                            float* __restrict__ ws) {
  int idx = blockIdx.x * 256 + threadIdx.x;
  if (idx < SCAL) {
    int p = idx >> 16;            // plane
    int rem = idx & 65535;
    int k = rem >> 9, g = rem & 511;
    float v;
    switch (p) {
      case 0:  v = Whh1[g * HH + k];         break;
      case 1:  v = Wih2[g * 129 + 1 + k];    break;
      case 2:  v = Whh2[g * HH + k];         break;
      case 3:  v = Wih3[g * 257 + 1 + k];    break;
      case 4:  v = Wih3[g * 257 + 129 + k];  break;
      default: v = Whh3[g * HH + k];         break;
    }
    ws[idx] = v;
  } else if (idx < WLIN) {
    int r = idx - SCAL;
    float v;
    if      (r < 512)  v = Wih1[r];
    else if (r < 1024) v = Wih2[(r - 512) * 129];
    else if (r < 1536) v = Wih3[(r - 1024) * 257];
    else if (r < 2048) v = bih1[r - 1536] + bhh1[r - 1536];
    else if (r < 2560) v = bih2[r - 2048] + bhh2[r - 2048];
    else               v = bih3[r - 2560] + bhh3[r - 2560];
    ws[idx] = v;
  } else if (idx < XT) {
    int j = idx - WLIN;
    ws[idx] = (j < 385) ? Wlin[j] : (j == 385 ? blin[0] : 0.0f);
  } else if (idx < RH1) {
    int j = idx - XT;
    int t = j >> 8, r = j & 255;
    ws[idx] = x[r * TSEQ + t];
  } else if (idx < PREP_TOT) {
    ws[FLAGS + (idx - RH1)] = 0.0f;   // zero flag lines (ws is poisoned)
  }
}

// ---------------------------------------------------------------------------
// G=4 K/8 dot for one row: 16 k-values, 4 gates of unit ud.
// hb pre-offset to the row base + kq*16. Returns acc as float4 (gate order).
__device__ __forceinline__ float4 dot16_g4(const float w[4][16],
                                           const float* __restrict__ hb) {
  float a0 = 0.f, a1 = 0.f, a2 = 0.f, a3 = 0.f;
  #pragma unroll
  for (int k4 = 0; k4 < 4; ++k4) {
    const float4 h4 = *(const float4*)&hb[k4 * 4];
    #pragma unroll
    for (int j = 0; j < 4; ++j) {
      const float hv = (j == 0) ? h4.x : (j == 1) ? h4.y : (j == 2) ? h4.z : h4.w;
      a0 = fmaf(w[0][4 * k4 + j], hv, a0);
      a1 = fmaf(w[1][4 * k4 + j], hv, a1);
      a2 = fmaf(w[2][4 * k4 + j], hv, a2);
      a3 = fmaf(w[3][4 * k4 + j], hv, a3);
    }
  }
  return make_float4(a0, a1, a2, a3);
}

// ---------------------------------------------------------------------------
// Core stage: gates = Whh*h_own (G=4 x K/8, permuted partials) + add-terms.
// DRH: dword offset of destination h ring.
template <int SSELF, int SWA, int SWB, int NP, int XF, int PB, int PR1, int PR2, int DRH>
__device__ void core_stage(float* __restrict__ wsm, char* SB, int g) {
  const int tid = threadIdx.x;              // [0,1024)
  const int r0 = g * 8;
  float* gs   = (float*)SB;                 // [8 rows][8 kq][512 colp] = 131072 B
  float* hown = (float*)(SB + 131072);      // [8][128] = 4096 B

  u64* ws64 = (u64*)wsm;
  unsigned* flagb = (unsigned*)wsm + FLAGS;
  unsigned* Fself = flagb + (size_t)(SSELF * 32 + g) * 32;
  unsigned* Fh    = flagb + (size_t)(6 * 32 + g) * 32;
  unsigned ca = 0, cb = 0, ch = 0;

  // dot role: unit ud owns gate cols {ud+128q}, k-range [kq*16, kq*16+16)
  const int ud = tid & 127, kq = tid >> 7;
  float w[4][16];
  #pragma unroll
  for (int q = 0; q < 4; ++q)
    #pragma unroll
    for (int k = 0; k < 16; ++k)
      w[q][k] = wsm[(size_t)PB * 65536 + (size_t)(kq * 16 + k) * 512 + ud + 128 * q];

  // combine+activation role: (row, u)
  const int row = tid >> 7, u = tid & 127;
  float xw4[4], bs4[4];
  if (XF) {
    #pragma unroll
    for (int q = 0; q < 4; ++q) {
      xw4[q] = wsm[SCAL + q * 128 + u];
      bs4[q] = wsm[SCAL + 1536 + q * 128 + u];
    }
  }

  hown[tid & 1023] = 0.f;                   // 8*128 = 1024 = blockDim
  float cst = 0.f;
  __syncthreads();

  for (int t = 0; t < TT; ++t) {
    if (tid == 0) {
      if constexpr (SWA >= 0)
        wait_c(flagb + (size_t)(SWA * 32 + g) * 32, (unsigned)(t + 1), ca);
      if constexpr (SWB >= 0)
        wait_c(flagb + (size_t)(SWB * 32 + g) * 32, (unsigned)(t + 1), cb);
      unsigned ht = (t >= 15) ? (unsigned)(t - 14) : 0u;
      if (XF && t >= TSEQ && (unsigned)t > ht) ht = (unsigned)t;
      if (ht) wait_c(Fh, ht, ch);
    }
    __syncthreads();                 // B1: inputs granted
    const int slot = t & 15;

    // combine-role prefetch: ring add-terms (HALF-SPLIT permutation):
    // gates{0,1} packed at u64 col u; gates{2,3} at u64 col 128+u.
    float pa[4], pb[4], xr;
    if constexpr (NP >= 1) {
      u64 l0 = __hip_atomic_load(
          ws64 + (size_t)(PR1 / 2) + (size_t)(t & 7) * 65536 +
              (size_t)(r0 + row) * 256 + u,
          __ATOMIC_RELAXED, __HIP_MEMORY_SCOPE_AGENT);
      u64 l1 = __hip_atomic_load(
          ws64 + (size_t)(PR1 / 2) + (size_t)(t & 7) * 65536 +
              (size_t)(r0 + row) * 256 + 128 + u,
          __ATOMIC_RELAXED, __HIP_MEMORY_SCOPE_AGENT);
      pa[0] = __builtin_bit_cast(float, (unsigned)(l0 & 0xffffffffu));
      pa[1] = __builtin_bit_cast(float, (unsigned)(l0 >> 32));
      pa[2] = __builtin_bit_cast(float, (unsigned)(l1 & 0xffffffffu));
      pa[3] = __builtin_bit_cast(float, (unsigned)(l1 >> 32));
    }
    if constexpr (NP == 2) {
      u64 l0 = __hip_atomic_load(
          ws64 + (size_t)(PR2 / 2) + (size_t)(t & 7) * 65536 +
              (size_t)(r0 + row) * 256 + u,
          __ATOMIC_RELAXED, __HIP_MEMORY_SCOPE_AGENT);
      u64 l1 = __hip_atomic_load(
          ws64 + (size_t)(PR2 / 2) + (size_t)(t & 7) * 65536 +
              (size_t)(r0 + row) * 256 + 128 + u,
          __ATOMIC_RELAXED, __HIP_MEMORY_SCOPE_AGENT);
      pb[0] = __builtin_bit_cast(float, (unsigned)(l0 & 0xffffffffu));
      pb[1] = __builtin_bit_cast(float, (unsigned)(l0 >> 32));
      pb[2] = __builtin_bit_cast(float, (unsigned)(l1 & 0xffffffffu));
      pb[3] = __builtin_bit_cast(float, (unsigned)(l1 >> 32));
    }
    if (XF) {
      if (t < TSEQ) {
        xr = wsm[XT + (size_t)t * 256 + r0 + row];
      } else {
        unsigned uu = __hip_atomic_load(
            (unsigned*)wsm + RO + (size_t)((t - 1) & 15) * 256 + r0 + row,
            __ATOMIC_RELAXED, __HIP_MEMORY_SCOPE_AGENT);
        xr = __builtin_bit_cast(float, uu);
      }
    }

    // dot: per row accumulate-then-store (acc live range = 4)
    #pragma unroll
    for (int a = 0; a < 8; ++a) {
      const float4 acc = dot16_g4(w, hown + a * HH + kq * 16);
      *(float4*)&gs[a * 4096 + kq * 512 + 4 * ud] = acc;
    }
    __syncthreads();                 // B2: partials visible

    // fused combine + activation: sum 8 contiguous-b128 partials
    {
      float gv0, gv1, gv2, gv3;
      if constexpr (NP == 0) {
        gv0 = fmaf(xw4[0], xr, bs4[0]);
        gv1 = fmaf(xw4[1], xr, bs4[1]);
        gv2 = fmaf(xw4[2], xr, bs4[2]);
        gv3 = fmaf(xw4[3], xr, bs4[3]);
      } else if constexpr (NP == 1) {
        gv0 = pa[0]; gv1 = pa[1]; gv2 = pa[2]; gv3 = pa[3];
      } else {
        gv0 = pa[0] + pb[0]; gv1 = pa[1] + pb[1];
        gv2 = pa[2] + pb[2]; gv3 = pa[3] + pb[3];
      }
      #pragma unroll
      for (int p = 0; p < 8; ++p) {
        const float4 f = *(const float4*)&gs[row * 4096 + p * 512 + 4 * u];
        gv0 += f.x; gv1 += f.y; gv2 += f.z; gv3 += f.w;
      }
      const float c = sigmoidf_(gv1) * cst + sigmoidf_(gv0) * tanhf(gv2);
      cst = c;
      const float h = sigmoidf_(gv3) * tanhf(c);
      hown[row * HH + u] = h;
      __hip_atomic_store(
          (unsigned*)wsm + DRH + (size_t)slot * 32768 + (size_t)(r0 + row) * 128 + u,
          __builtin_bit_cast(unsigned, h),
          __ATOMIC_RELAXED, __HIP_MEMORY_SCOPE_AGENT);
    }
    __syncthreads();                 // B3: hown visible, stores drained
    if (tid == 0)
      __hip_atomic_fetch_add(Fself, 1u, __ATOMIC_RELAXED, __HIP_MEMORY_SCOPE_AGENT);
  }
}

// ---------------------------------------------------------------------------
// Helper stage: partial = [x-term+bias if XF] + Wpart * h_src(t) (G=4 x K/8,
// permuted partials); combine; publish HALF-SPLIT to partial ring:
// gates{0,1} -> u64 col u (lane-consecutive), gates{2,3} -> u64 col 128+u.
// SC: DIRECT-CONSUMER stage id for the RP anti-dep (>= t-6, strict t-7).
template <int SSELF, int SW, int SC, int XF, int PB, int SI, int SRH64, int DRP>
__device__ void helper_stage(float* __restrict__ wsm, char* SB, int g) {
  const int tid = threadIdx.x;
  const int r0 = g * 8;
  float* ps  = (float*)SB;                  // [8][8][512] = 131072 B
  float* hin = (float*)(SB + 131072);       // [8][128] = 4096 B
  float* xs  = (float*)(SB + 135168);       // [8]

  u64* ws64 = (u64*)wsm;
  unsigned* flagb = (unsigned*)wsm + FLAGS;
  unsigned* Fself = flagb + (size_t)(SSELF * 32 + g) * 32;
  unsigned* Fw    = flagb + (size_t)(SW * 32 + g) * 32;
  unsigned* Fc    = flagb + (size_t)(SC * 32 + g) * 32;
  unsigned* Fhd   = flagb + (size_t)(6 * 32 + g) * 32;
  unsigned cw = 0, cc = 0, chd = 0;

  const int ud = tid & 127, kq = tid >> 7;
  float w[4][16];
  #pragma unroll
  for (int q = 0; q < 4; ++q)
    #pragma unroll
    for (int k = 0; k < 16; ++k)
      w[q][k] = wsm[(size_t)PB * 65536 + (size_t)(kq * 16 + k) * 512 + ud + 128 * q];

  const int row = tid >> 7, u = tid & 127;
  float xw4[4], bs4[4];
  if (XF) {
    #pragma unroll
    for (int q = 0; q < 4; ++q) {
      xw4[q] = wsm[SCAL + SI * 512 + q * 128 + u];
      bs4[q] = wsm[SCAL + 1536 + SI * 512 + q * 128 + u];
    }
  }
  __syncthreads();

  for (int t = 0; t < TT; ++t) {
    if (tid == 0) {
      wait_c(Fw, (unsigned)(t + 1), cw);
      if (t >= 7) wait_c(Fc, (unsigned)(t - 6), cc);
      if (XF && t >= TSEQ) wait_c(Fhd, (unsigned)t, chd);
    }
    __syncthreads();                 // B1: inputs granted
    const int slot = t & 15;

    if (XF) {
      if (tid < 8) {
        float xv;
        if (t < TSEQ) {
          xv = wsm[XT + (size_t)t * 256 + r0 + tid];
        } else {
          unsigned uu = __hip_atomic_load(
              (unsigned*)wsm + RO + (size_t)((t - 1) & 15) * 256 + r0 + tid,
              __ATOMIC_RELAXED, __HIP_MEMORY_SCOPE_AGENT);
          xv = __builtin_bit_cast(float, uu);
        }
        xs[tid] = xv;
      }
    }
    // stage h_src(t): 512 u64 / first 512 threads
    if (tid < 512) {
      const int a = tid >> 6, up = tid & 63;
      u64 v = __hip_atomic_load(
          ws64 + SRH64 + (size_t)slot * 16384 + (size_t)(r0 + a) * 64 + up,
          __ATOMIC_RELAXED, __HIP_MEMORY_SCOPE_AGENT);
      *(u64*)&hin[a * HH + up * 2] = v;
    }
    __syncthreads();                 // B2: hin (and xs) visible

    // dot: per row accumulate-then-store
    #pragma unroll
    for (int a = 0; a < 8; ++a) {
      const float4 acc = dot16_g4(w, hin + a * HH + kq * 16);
      *(float4*)&ps[a * 4096 + kq * 512 + 4 * ud] = acc;
    }
    __syncthreads();                 // B3: partials visible

    // combine + publish (HALF-SPLIT ring: lane-consecutive u64 stores)
    {
      float v0, v1, v2, v3;
      if (XF) {
        const float xv = xs[row];
        v0 = fmaf(xw4[0], xv, bs4[0]);
        v1 = fmaf(xw4[1], xv, bs4[1]);
        v2 = fmaf(xw4[2], xv, bs4[2]);
        v3 = fmaf(xw4[3], xv, bs4[3]);
      } else {
        v0 = v1 = v2 = v3 = 0.f;
      }
      #pragma unroll
      for (int p = 0; p < 8; ++p) {
        const float4 f = *(const float4*)&ps[row * 4096 + p * 512 + 4 * u];
        v0 += f.x; v1 += f.y; v2 += f.z; v3 += f.w;
      }
      const u64 s0 = ((u64)__builtin_bit_cast(unsigned, v1) << 32) |
                     (u64)__builtin_bit_cast(unsigned, v0);
      const u64 s1 = ((u64)__builtin_bit_cast(unsigned, v3) << 32) |
                     (u64)__builtin_bit_cast(unsigned, v2);
      __hip_atomic_store(
          ws64 + (size_t)(DRP / 2) + (size_t)(t & 7) * 65536 +
              (size_t)(r0 + row) * 256 + u, s0,
          __ATOMIC_RELAXED, __HIP_MEMORY_SCOPE_AGENT);
      __hip_atomic_store(
          ws64 + (size_t)(DRP / 2) + (size_t)(t & 7) * 65536 +
              (size_t)(r0 + row) * 256 + 128 + u, s1,
          __ATOMIC_RELAXED, __HIP_MEMORY_SCOPE_AGENT);
    }
    __syncthreads();                 // B4: ring stores drained
    if (tid == 0)
      __hip_atomic_fetch_add(Fself, 1u, __ATOMIC_RELAXED, __HIP_MEMORY_SCOPE_AGENT);
  }
}

// ---------------------------------------------------------------------------
__device__ void head_stage(float* __restrict__ wsm, char* SB, int g,
                           float* __restrict__ out) {
  const int tid = threadIdx.x;
  const int r0 = g * 8;
  float* hin  = (float*)SB;                 // [3][8][128] = 12288 B
  float* obuf = (float*)(SB + 12288);       // [8][32]

  u64* ws64 = (u64*)wsm;
  unsigned* flagb = (unsigned*)wsm + FLAGS;
  unsigned* Fself = flagb + (size_t)(6 * 32 + g) * 32;
  unsigned* Fc3   = flagb + (size_t)(5 * 32 + g) * 32;
  unsigned c3c = 0;

  const int row = (tid >> 6) & 7, lane = tid & 63;
  float wlr[6];
  #pragma unroll
  for (int q = 0; q < 6; ++q) wlr[q] = wsm[WLIN + 1 + lane + 64 * q];
  const float wl0 = wsm[WLIN];
  const float blv = wsm[WLIN + 385];
  float xv = wsm[XT + r0 + row];

  for (int t = 0; t < TT; ++t) {
    if (tid == 0) wait_c(Fc3, (unsigned)(t + 1), c3c);
    __syncthreads();                 // B1
    const int slot = t & 15;

    #pragma unroll
    for (int i = 0; i < 2; ++i) {
      const int idx = tid + i * 1024;       // 0..2047, use 0..1535
      if (idx < 1536) {
        const int s = idx >> 9, rem = idx & 511;
        const int a = rem >> 6, up = rem & 63;
        const size_t base = (s == 0) ? (size_t)RH1_64 : (s == 1) ? (size_t)RH2_64 : (size_t)RH3_64;
        u64 v = __hip_atomic_load(
            ws64 + base + (size_t)slot * 16384 + (size_t)(r0 + a) * 64 + up,
            __ATOMIC_RELAXED, __HIP_MEMORY_SCOPE_AGENT);
        *(u64*)&hin[(s * 8 + a) * HH + up * 2] = v;
      }
    }
    __syncthreads();                 // B2

    if (tid < 512) {
      float s = 0.f;
      #pragma unroll
      for (int q = 0; q < 6; ++q) {
        const int j = lane + 64 * q;        // 0..383
        const int si = j >> 7, uu = j & 127;
        s = fmaf(wlr[q], hin[(si * 8 + row) * HH + uu], s);
      }
      #pragma unroll
      for (int off = 32; off > 0; off >>= 1) s += __shfl_down(s, off, 64);
      if (lane == 0) {
        const float o = s + fmaf(wl0, xv, blv);
        obuf[row * 32 + (t & 31)] = o;
        __hip_atomic_store((unsigned*)wsm + RO + (size_t)slot * 256 + r0 + row,
                           __builtin_bit_cast(unsigned, o),
                           __ATOMIC_RELAXED, __HIP_MEMORY_SCOPE_AGENT);
        xv = (t + 1 < TSEQ) ? wsm[XT + (size_t)(t + 1) * 256 + r0 + row] : o;
      }
    }
    __syncthreads();                 // B3: o-store + obuf drained
    if (tid == 0)
      __hip_atomic_fetch_add(Fself, 1u, __ATOMIC_RELAXED, __HIP_MEMORY_SCOPE_AGENT);

    if ((t & 31) == 31) {
      const int tb = t - 31;
      if (tid < 256) {
        const int a = tid >> 5, m = tid & 31;
        out[(size_t)(r0 + a) * TT + tb + m] = obuf[a * 32 + m];
      }
    }
  }
}

// ---------------------------------------------------------------------------
__global__ __launch_bounds__(1024)
void lstm_kernel(float* __restrict__ wsm, float* __restrict__ out) {
  __shared__ __align__(16) char SB[135232];
  const int s = blockIdx.x >> 5, g = blockIdx.x & 31;
  switch (s) {
    case 0: core_stage<0, -1, -1, 0, 1, 0, 0, 0, RH1>(wsm, SB, g); break;
    case 1: helper_stage<1, 0, 2, 1, 1, 1, RH1_64, RP2>(wsm, SB, g); break;
    case 2: core_stage<2, 1, -1, 1, 0, 2, RP2, 0, RH2>(wsm, SB, g); break;
    case 3: helper_stage<3, 0, 5, 1, 3, 2, RH1_64, RP3A>(wsm, SB, g); break;
    case 4: helper_stage<4, 2, 5, 0, 4, 0, RH2_64, RP3B>(wsm, SB, g); break;
    case 5: core_stage<5, 3, 4, 2, 0, 5, RP3A, RP3B, RH3>(wsm, SB, g); break;
    default: head_stage(wsm, SB, g, out); break;
  }
}

// ---------------------------------------------------------------------------
extern "C" void kernel_launch(void* const* d_in, const int* in_sizes, int n_in,
                              void* d_out, int out_size, void* d_ws, size_t ws_size,
                              hipStream_t stream) {
  const float* x    = (const float*)d_in[0];
  const float* Wih1 = (const float*)d_in[1];
  const float* Whh1 = (const float*)d_in[2];
  const float* bih1 = (const float*)d_in[3];
  const float* bhh1 = (const float*)d_in[4];
  const float* Wih2 = (const float*)d_in[5];
  const float* Whh2 = (const float*)d_in[6];
  const float* bih2 = (const float*)d_in[7];
  const float* bhh2 = (const float*)d_in[8];
  const float* Wih3 = (const float*)d_in[9];
  const float* Whh3 = (const float*)d_in[10];
  const float* bih3 = (const float*)d_in[11];
  const float* bhh3 = (const float*)d_in[12];
  const float* Wlin = (const float*)d_in[13];
  const float* blin = (const float*)d_in[14];
  float* ws  = (float*)d_ws;
  float* out = (float*)d_out;

  prep_kernel<<<PREP_TOT / 256, 256, 0, stream>>>(
      x, Wih1, Whh1, bih1, bhh1, Wih2, Whh2, bih2, bhh2,
      Wih3, Whh3, bih3, bhh3, Wlin, blin, ws);
  lstm_kernel<<<224, THR, 0, stream>>>(ws, out);
}